// Round 2
// baseline (838.594 us; speedup 1.0000x reference)
//
#include <hip/hip_runtime.h>

// select_decoder_vectors: out[i,:] = values[i] * W_D[layer_idx[i], feat_idx[i], :]
// Shapes: W_D (12, 16384, 768) f32, nnz = 131072, d_model = 768.
// Memory-bound gather. One wave handles TWO consecutive nnz rows (doubles
// memory-level parallelism: 6 outstanding float4 loads/lane instead of 3).
// Output is written with nontemporal stores: it is write-once/never-read, so
// keeping it out of L2/L3 preserves cache capacity for duplicate W_D rows
// (~1.37x gather reuse; unique read footprint ~294 MB vs 256 MB L3).
//
// NOTE: __builtin_nontemporal_store requires a native clang vector type,
// not HIP's float4 class -> use ext_vector_type(4).

#define D_MODEL 768
#define D_SAE   16384
#define WAVES_PER_BLOCK 4
#define ROWS_PER_WAVE   2
#define ROWS_PER_BLOCK  (WAVES_PER_BLOCK * ROWS_PER_WAVE)   // 8

typedef float f32x4 __attribute__((ext_vector_type(4)));

__global__ __launch_bounds__(256) void gather_scale_kernel(
    const float* __restrict__ W_D,
    const float* __restrict__ values,
    const int*   __restrict__ layer_idx,
    const int*   __restrict__ feat_idx,
    float*       __restrict__ out,
    int nnz)
{
    const int wave_in_block = threadIdx.x >> 6;
    const int lane          = threadIdx.x & 63;
    const int row0 = blockIdx.x * ROWS_PER_BLOCK + wave_in_block * ROWS_PER_WAVE;
    if (row0 >= nnz) return;

    const bool has_r1 = (row0 + 1) < nnz;   // nnz=131072 is a multiple of 8, but stay safe
    const int  row1   = has_r1 ? (row0 + 1) : row0;

    // Per-row scalars (wave-uniform; ~12 B/row, negligible traffic).
    const float v0 = values[row0];
    const float v1 = values[row1];
    const long long sr0 = (long long)layer_idx[row0] * D_SAE + feat_idx[row0];
    const long long sr1 = (long long)layer_idx[row1] * D_SAE + feat_idx[row1];

    const f32x4* __restrict__ src0 = (const f32x4*)(W_D + sr0 * D_MODEL);
    const f32x4* __restrict__ src1 = (const f32x4*)(W_D + sr1 * D_MODEL);
    f32x4* __restrict__ dst0 = (f32x4*)(out + (long long)row0 * D_MODEL);
    f32x4* __restrict__ dst1 = (f32x4*)(out + (long long)row1 * D_MODEL);

    // Issue all 6 loads first (max MLP), then scale + nontemporal-store.
    f32x4 a[3], b[3];
    #pragma unroll
    for (int i = 0; i < 3; ++i) a[i] = src0[lane + 64 * i];
    #pragma unroll
    for (int i = 0; i < 3; ++i) b[i] = src1[lane + 64 * i];

    #pragma unroll
    for (int i = 0; i < 3; ++i) {
        __builtin_nontemporal_store(a[i] * v0, &dst0[lane + 64 * i]);
    }
    if (has_r1) {
        #pragma unroll
        for (int i = 0; i < 3; ++i) {
            __builtin_nontemporal_store(b[i] * v1, &dst1[lane + 64 * i]);
        }
    }
}

extern "C" void kernel_launch(void* const* d_in, const int* in_sizes, int n_in,
                              void* d_out, int out_size, void* d_ws, size_t ws_size,
                              hipStream_t stream) {
    const float* W_D       = (const float*)d_in[0];
    const float* values    = (const float*)d_in[1];
    const int*   layer_idx = (const int*)d_in[2];
    // d_in[3] = pos_idx (unused by reference)
    const int*   feat_idx  = (const int*)d_in[4];
    float*       out       = (float*)d_out;

    const int nnz = in_sizes[1];  // 131072
    const int blocks = (nnz + ROWS_PER_BLOCK - 1) / ROWS_PER_BLOCK;
    gather_scale_kernel<<<blocks, 256, 0, stream>>>(W_D, values, layer_idx, feat_idx, out, nnz);
}